// Round 2
// baseline (1114.900 us; speedup 1.0000x reference)
//
#include <hip/hip_runtime.h>
#include <hip/hip_bf16.h>

#define N_ 4
#define C_ 512
#define CI_ 256
#define S_ 6272
#define EPS_ 1e-5f
#define NKT 98        // key tiles (of 32) per split; 2 splits * 98 * 32 = 6272

typedef __attribute__((ext_vector_type(8))) __bf16 bf16x8;
typedef __attribute__((ext_vector_type(4))) __bf16 bf16x4;
typedef __attribute__((ext_vector_type(4))) float f32x4;

#define MFMA(a, b, c) __builtin_amdgcn_mfma_f32_16x16x32_bf16(a, b, c, 0, 0, 0)

__device__ __forceinline__ void gl_lds16(const void* g, void* l) {
    __builtin_amdgcn_global_load_lds(
        (const __attribute__((address_space(1))) void*)g,
        (__attribute__((address_space(3))) void*)l, 16, 0, 0);
}

// barrier that drains only LDS ops (leaves global_load_lds DMAs in flight)
#define BARRIER_LGKM() asm volatile("s_waitcnt lgkmcnt(0)\n\ts_barrier" ::: "memory")
// order-only fence: my LDS reads are in registers before anything after this issues
#define FENCE_LGKM()   asm volatile("s_waitcnt lgkmcnt(0)" ::: "memory")
// full-drain barrier: all my DMAs landed; barrier -> everyone's landed
#define BARRIER_VM0()  asm volatile("s_waitcnt vmcnt(0)\n\ts_barrier" ::: "memory")

// ---------------- Kernel 1: QKV projections ----------------
// M = ci (128/block), N = s (64/block), K = c.  Outputs:
//   theta[n][s][ci], phi[n][s][ci] (bf16, PRE-SCALED by 0.25 each; exact since
//   0.25 is a power of two -> theta.phi = scores * ci^-0.5 directly)
//   gT[n][ci][s] (bf16)
__global__ __launch_bounds__(256) void qkv_kernel(
    const float* __restrict__ x,
    const float* __restrict__ w_theta, const float* __restrict__ b_theta,
    const float* __restrict__ w_phi,   const float* __restrict__ b_phi,
    const float* __restrict__ w_g,     const float* __restrict__ b_g,
    __bf16* __restrict__ theta, __bf16* __restrict__ phi, __bf16* __restrict__ gT)
{
    const int s0  = blockIdx.x * 64;
    const int ci0 = blockIdx.y * 128;
    const int n   = blockIdx.z;
    const int tid = threadIdx.x;
    const int wave = tid >> 6, lane = tid & 63;
    const int m16 = lane & 15, quad = lane >> 4;

    __shared__ __bf16 xT[64][40];  // [s-local][c-local(32)], pad->40

    const float* wptr[3] = {w_theta, w_phi, w_g};

    f32x4 acc[3][2][4];
    #pragma unroll
    for (int j = 0; j < 3; ++j)
        #pragma unroll
        for (int ct = 0; ct < 2; ++ct)
            #pragma unroll
            for (int ss = 0; ss < 4; ++ss) acc[j][ct][ss] = f32x4{0.f, 0.f, 0.f, 0.f};

    const int ci_row[2] = {ci0 + wave * 16 + m16, ci0 + 64 + wave * 16 + m16};

    for (int kc = 0; kc < 16; ++kc) {
        __syncthreads();
        // stage x[n][kc*32+c][s0..s0+64] -> xT[s][c]  (float4 along s)
        #pragma unroll
        for (int it = 0; it < 2; ++it) {
            int c_loc = it * 16 + (tid >> 4);
            int s4 = (tid & 15) * 4;
            float4 v = *(const float4*)&x[((size_t)n * C_ + kc * 32 + c_loc) * S_ + s0 + s4];
            xT[s4 + 0][c_loc] = (__bf16)v.x;
            xT[s4 + 1][c_loc] = (__bf16)v.y;
            xT[s4 + 2][c_loc] = (__bf16)v.z;
            xT[s4 + 3][c_loc] = (__bf16)v.w;
        }
        __syncthreads();

        bf16x8 afr[3][2];
        #pragma unroll
        for (int j = 0; j < 3; ++j)
            #pragma unroll
            for (int ct = 0; ct < 2; ++ct) {
                const float* wp = wptr[j] + (size_t)ci_row[ct] * C_ + kc * 32 + quad * 8;
                float4 wa = *(const float4*)wp;
                float4 wb = *(const float4*)(wp + 4);
                bf16x8 t;
                t[0] = (__bf16)wa.x; t[1] = (__bf16)wa.y; t[2] = (__bf16)wa.z; t[3] = (__bf16)wa.w;
                t[4] = (__bf16)wb.x; t[5] = (__bf16)wb.y; t[6] = (__bf16)wb.z; t[7] = (__bf16)wb.w;
                afr[j][ct] = t;
            }
        #pragma unroll
        for (int ss = 0; ss < 4; ++ss) {
            bf16x8 bfr = *(const bf16x8*)&xT[ss * 16 + m16][quad * 8];
            #pragma unroll
            for (int j = 0; j < 3; ++j)
                #pragma unroll
                for (int ct = 0; ct < 2; ++ct)
                    acc[j][ct][ss] = MFMA(afr[j][ct], bfr, acc[j][ct][ss]);
        }
    }

    #pragma unroll
    for (int ct = 0; ct < 2; ++ct) {
        const int ci_base = ci0 + ct * 64 + wave * 16 + quad * 4;
        float bth[4], bph[4], bgg[4];
        #pragma unroll
        for (int r = 0; r < 4; ++r) {
            bth[r] = b_theta[ci_base + r];
            bph[r] = b_phi[ci_base + r];
            bgg[r] = b_g[ci_base + r];
        }
        #pragma unroll
        for (int ss = 0; ss < 4; ++ss) {
            int s = s0 + ss * 16 + m16;
            bf16x4 tv, pv;
            #pragma unroll
            for (int r = 0; r < 4; ++r) {
                tv[r] = (__bf16)((acc[0][ct][ss][r] + bth[r]) * 0.25f);
                pv[r] = (__bf16)((acc[1][ct][ss][r] + bph[r]) * 0.25f);
            }
            *(bf16x4*)&theta[((size_t)n * S_ + s) * CI_ + ci_base] = tv;
            *(bf16x4*)&phi[((size_t)n * S_ + s) * CI_ + ci_base]   = pv;
            #pragma unroll
            for (int r = 0; r < 4; ++r)
                gT[((size_t)n * CI_ + ci_base + r) * S_ + s] = (__bf16)(acc[2][ct][ss][r] + bgg[r]);
        }
    }
}

// ---------------- Kernel 2: flash attention ----------------
// R6 restructure (occupancy): single-buffered K AND V at 32-key tiles ->
// LDS = 16K(K) + 16K(V) + 5K(P) + 0.5K = 38.4 KB -> 4 blocks/CU (was 2),
// 16 waves/CU (VGPR 104 <= 128, __launch_bounds__(256,4)).  All 784 blocks
// co-resident (1024 slots) -> no second-round tail.
// R1 evidence: FETCH 139->37 MB with no dur change => not BW-bound; MfmaUtil
// 30% == the arithmetic for 2 blocks/CU latency-serialized chain.  More
// resident blocks is the lever; the counted-vmcnt dbuf pipeline was not.
// Hazard scheme (R0-proven, 32-key):
//   * top BARRIER_VM0: my 8 DMAs (K(t),V(t), issued last iter) landed; barrier
//     -> everyone's landed.  K DMAs ride through PV (~600cy), V through the
//     PV MFMA block (~300cy) -> L2-hit latency (~200cy) covered.
//   * mid BARRIER_LGKM: P visible; all waves' kf reads drained -> K overwrite
//     safe.  STAGE_K(t+1) immediately after.
//   * V rows are WAVE-PRIVATE (wave stages and reads only rows [w*64,+64));
//     FENCE_LGKM puts own vf reads in registers -> STAGE_V(t+1) safe.
//   * P WAR: pf reads (before FENCE) < top barrier < next-iter P writes.
// XCD swizzle kept: grp = bid&7 = (n,split) -> one XCD each; K/V panel 3.2 MB
// < 4 MB XCD-L2 (R1: FETCH_SIZE 4x drop confirms it works).
__global__ __launch_bounds__(256, 4) void attn_kernel(
    const __bf16* __restrict__ theta, const __bf16* __restrict__ phi,
    const __bf16* __restrict__ gT, __bf16* __restrict__ Opart, float* __restrict__ lpart)
{
    const int bid = blockIdx.x;
    const int grp = bid & 7;            // (n,split) group -> XCD grp
    const int q0 = (bid >> 3) * 64;
    const int n = grp >> 1;
    const int split = grp & 1;
    const int tid = threadIdx.x;
    const int w = tid >> 6, lane = tid & 63;
    const int m16 = lane & 15, quad = lane >> 4;
    const int xr = m16 & 7;
    const int h = w & 1, kh = w >> 1;

    extern __shared__ char smem[];
    __bf16* k_lds = (__bf16*)smem;                  // [32][256] swizzled (16384 B)
    __bf16* v_lds = (__bf16*)(smem + 16384);        // [256][32] swizzled (16384 B)
    __bf16* p_lds = (__bf16*)(smem + 32768);        // [64][40]  (5120 B)
    float*  lsum  = (float*)(smem + 37888);         // [64][2]   (512 B)

    // ---- Q B-frags: this wave's 32 queries (q-half h) -> 64 VGPR ----
    bf16x8 qreg[2][8];
    #pragma unroll
    for (int qf = 0; qf < 2; ++qf) {
        const __bf16* qrow = theta + ((size_t)n * S_ + q0 + h * 32 + qf * 16 + m16) * CI_ + quad * 8;
        #pragma unroll
        for (int kk = 0; kk < 8; ++kk) qreg[qf][kk] = *(const bf16x8*)(qrow + kk * 32);
    }

    // ---- staging bases (wave w stages K rows [w*8,+8), V rows [w*64,+64)) ----
    const int krow_loc = lane >> 5;                 // 0..1
    const int kA = (lane & 31) ^ krow_loc;
    const char* kgbase = (const char*)(phi + ((size_t)n * S_ + (size_t)split * 3136 + w * 8) * CI_)
                         + krow_loc * 512;
    char* klbase = (char*)k_lds + w * 4096;

    const int vrow_loc = lane >> 2;                 // 0..15
    const int vchunk = (lane & 3) ^ ((lane >> 3) & 3);   // src chunk = pos ^ ((row>>1)&3)
    const char* vgbase = (const char*)gT + (((size_t)n * CI_ + w * 64 + vrow_loc) * S_
                         + (size_t)split * 3136) * 2 + vchunk * 16;
    char* vlbase = (char*)v_lds + w * 4096;

    #define STAGE_K(kt_) { \
        const char* gk = kgbase + ((size_t)(kt_) << 14); \
        _Pragma("unroll") \
        for (int j = 0; j < 4; ++j) \
            gl_lds16(gk + j * 1024 + ((kA ^ ((2 * j) & 7)) << 4), klbase + j * 1024); \
        }
    #define STAGE_V(kt_) { \
        const char* gv = vgbase + (size_t)(kt_) * 64; \
        _Pragma("unroll") \
        for (int j = 0; j < 4; ++j) \
            gl_lds16(gv + (size_t)j * 200704, vlbase + j * 1024); \
        }

    f32x4 o[4][4];  // [c][qf] -> o[ci = w*64+c*16+quad*4+r][q = qf*16+m16]
    #pragma unroll
    for (int c = 0; c < 4; ++c)
        #pragma unroll
        for (int qf = 0; qf < 4; ++qf) o[c][qf] = f32x4{0.f, 0.f, 0.f, 0.f};
    float l_part[2] = {0.f, 0.f};

    const __bf16* krow_base = k_lds + ((kh * 16 + m16) << 8);
    const __bf16* vrow_base = v_lds + ((w * 64 + m16) << 5) + ((quad ^ ((m16 >> 1) & 3)) << 3);

    // prologue: tile 0 in flight (8 DMAs)
    STAGE_K(0); STAGE_V(0);

    for (int kt = 0; kt < NKT; ++kt) {
        BARRIER_VM0();   // K(t), V(t) staged & visible in all waves; p_lds WAR

        // ---- QK^T quadrant: D[m = key kh*16+quad*4+r][n = q-half h, qf*16+m16] ----
        f32x4 sc[2];
        sc[0] = f32x4{0.f, 0.f, 0.f, 0.f};
        sc[1] = f32x4{0.f, 0.f, 0.f, 0.f};
        #pragma unroll
        for (int kk = 0; kk < 8; ++kk) {
            bf16x8 kf = *(const bf16x8*)(krow_base + (((kk * 4 + quad) ^ xr) << 3));
            sc[0] = MFMA(kf, qreg[0][kk], sc[0]);
            sc[1] = MFMA(kf, qreg[1][kk], sc[1]);
        }

        // ---- exp (pre-scaled scores, no max shift), l accum, P -> LDS [q][key] ----
        #pragma unroll
        for (int qf = 0; qf < 2; ++qf) {
            bf16x4 pk;
            float ls = 0.f;
            #pragma unroll
            for (int r = 0; r < 4; ++r) {
                float e = __expf(sc[qf][r]);
                ls += e;
                pk[r] = (__bf16)e;
            }
            l_part[qf] += ls;
            *(bf16x4*)&p_lds[(h * 32 + qf * 16 + m16) * 40 + kh * 16 + quad * 4] = pk;
        }
        BARRIER_LGKM();   // P visible; all waves' kf reads drained -> K buffer free

        if (kt + 1 < NKT) STAGE_K(kt + 1);   // rides through PV, drains at next top barrier

        // ---- PV: D[m = ci(own 64)][n = q 64] over k = 32 (single K-step) ----
        bf16x8 pf[4], vf[4];
        #pragma unroll
        for (int qf = 0; qf < 4; ++qf)
            pf[qf] = *(const bf16x8*)&p_lds[(qf * 16 + m16) * 40 + quad * 8];
        #pragma unroll
        for (int c = 0; c < 4; ++c)
            vf[c] = *(const bf16x8*)(vrow_base + c * 512);
        if (kt + 1 < NKT) {
            FENCE_LGKM();                 // vf/pf in registers -> own V rows overwrite-safe
            STAGE_V(kt + 1);
        }
        #pragma unroll
        for (int c = 0; c < 4; ++c)
            #pragma unroll
            for (int qf = 0; qf < 4; ++qf)
                o[c][qf] = MFMA(vf[c], pf[qf], o[c][qf]);
    }

    // ---- l: sum over quads (own 16 keys), then combine key-halves via LDS ----
    #pragma unroll
    for (int qf = 0; qf < 2; ++qf) {
        float l = l_part[qf];
        l += __shfl_xor(l, 16);
        l += __shfl_xor(l, 32);
        if (quad == 0) lsum[(h * 32 + qf * 16 + m16) * 2 + kh] = l;
    }
    __syncthreads();
    if (tid < 64)
        lpart[((size_t)split * N_ + n) * S_ + q0 + tid] = lsum[tid * 2] + lsum[tid * 2 + 1];

    // ---- store unnormalized O partial ----
    __bf16* Op = Opart + (size_t)split * N_ * S_ * CI_;
    #pragma unroll
    for (int c = 0; c < 4; ++c)
        #pragma unroll
        for (int qf = 0; qf < 4; ++qf) {
            bf16x4 ov;
            #pragma unroll
            for (int r = 0; r < 4; ++r) ov[r] = (__bf16)o[c][qf][r];
            *(bf16x4*)&Op[((size_t)n * S_ + q0 + qf * 16 + m16) * CI_ + w * 64 + c * 16 + quad * 4] = ov;
        }
}

// ---------------- Kernel 3: w_out GEMM + fused split-combine + BN partial stats ----------------
__global__ __launch_bounds__(256) void pgemm_kernel(
    const __bf16* __restrict__ Opart, const float* __restrict__ lpart,
    const float* __restrict__ w_out, const float* __restrict__ b_out,
    __bf16* __restrict__ p, float* __restrict__ ssum, float* __restrict__ ssq)
{
    const int s0 = blockIdx.x * 64;
    const int c0 = blockIdx.y * 128;
    const int n  = blockIdx.z;
    const int tid = threadIdx.x;
    const int wave = tid >> 6, lane = tid & 63;
    const int m16 = lane & 15, quad = lane >> 4;

    __shared__ __bf16 o_lds[64][264];

    const __bf16* O0 = Opart;
    const __bf16* O1 = Opart + (size_t)N_ * S_ * CI_;
    #pragma unroll
    for (int it = 0; it < 8; ++it) {
        int idx = it * 256 + tid;
        int row = idx >> 5, ch = idx & 31;
        size_t ns = (size_t)n * S_ + s0 + row;
        float li = 1.0f / (lpart[ns] + lpart[(size_t)N_ * S_ + ns]);
        bf16x8 a = *(const bf16x8*)&O0[ns * CI_ + ch * 8];
        bf16x8 b = *(const bf16x8*)&O1[ns * CI_ + ch * 8];
        bf16x8 t;
        #pragma unroll
        for (int e = 0; e < 8; ++e) t[e] = (__bf16)(((float)a[e] + (float)b[e]) * li);
        *(bf16x8*)&o_lds[row][ch * 8] = t;
    }
    __syncthreads();

    #pragma unroll
    for (int ct = 0; ct < 2; ++ct) {
        const int c_row = c0 + ct * 64 + wave * 16 + m16;
        bf16x8 af[8];
        #pragma unroll
        for (int kk = 0; kk < 8; ++kk) {
            const float* wp = w_out + (size_t)c_row * CI_ + kk * 32 + quad * 8;
            float4 wa = *(const float4*)wp;
            float4 wb = *(const float4*)(wp + 4);
            bf16x8 t;
            t[0] = (__bf16)wa.x; t[1] = (__bf16)wa.y; t[2] = (__bf16)wa.z; t[3] = (__bf16)wa.w;
            t[4] = (__bf16)wb.x; t[5] = (__bf16)wb.y; t[6] = (__bf16)wb.z; t[7] = (__bf16)wb.w;
            af[kk] = t;
        }
        f32x4 acc[4];
        #pragma unroll
        for (int ss = 0; ss < 4; ++ss) acc[ss] = f32x4{0.f, 0.f, 0.f, 0.f};
        #pragma unroll
        for (int ss = 0; ss < 4; ++ss)
            #pragma unroll
            for (int kk = 0; kk < 8; ++kk) {
                bf16x8 bfr = *(const bf16x8*)&o_lds[ss * 16 + m16][kk * 32 + quad * 8];
                acc[ss] = MFMA(af[kk], bfr, acc[ss]);
            }

        const int c_base = c0 + ct * 64 + wave * 16 + quad * 4;
        float bo[4];
        #pragma unroll
        for (int r = 0; r < 4; ++r) bo[r] = b_out[c_base + r];
        float psum[4] = {0.f, 0.f, 0.f, 0.f}, psq[4] = {0.f, 0.f, 0.f, 0.f};
        #pragma unroll
        for (int ss = 0; ss < 4; ++ss) {
            int s = s0 + ss * 16 + m16;
            #pragma unroll
            for (int r = 0; r < 4; ++r) {
                float v = acc[ss][r] + bo[r];
                __bf16 vb = (__bf16)v;
                p[((size_t)n * C_ + c_base + r) * S_ + s] = vb;
                float vr = (float)vb;
                psum[r] += vr;
                psq[r]  += vr * vr;
            }
        }
        #pragma unroll
        for (int r = 0; r < 4; ++r) {
            #pragma unroll
            for (int off = 1; off < 16; off <<= 1) {
                psum[r] += __shfl_xor(psum[r], off);
                psq[r]  += __shfl_xor(psq[r], off);
            }
        }
        if (m16 == 0) {
            #pragma unroll
            for (int r = 0; r < 4; ++r) {
                atomicAdd(&ssum[c_base + r], psum[r]);
                atomicAdd(&ssq[c_base + r],  psq[r]);
            }
        }
    }
}

// ---------------- small kernels ----------------
__global__ void zero_stats(float* ptr) {
    ptr[blockIdx.x * blockDim.x + threadIdx.x] = 0.0f;
}

__global__ void stats_kernel(const float* __restrict__ ssum, const float* __restrict__ ssq,
                             const float* __restrict__ gamma, const float* __restrict__ beta,
                             float* __restrict__ sc, float* __restrict__ sh)
{
    int c = threadIdx.x;  // 512
    const float inv_m = 1.0f / (float)((size_t)N_ * S_);
    float mean = ssum[c] * inv_m;
    float var = ssq[c] * inv_m - mean * mean;
    var = fmaxf(var, 0.0f);
    float inv = rsqrtf(var + EPS_);
    float g = gamma[c];
    sc[c] = inv * g;
    sh[c] = beta[c] - mean * inv * g;
}

__global__ __launch_bounds__(256) void apply_kernel(
    const float* __restrict__ x, const __bf16* __restrict__ p,
    const float* __restrict__ sc, const float* __restrict__ sh,
    float* __restrict__ out)
{
    size_t i4 = (size_t)blockIdx.x * blockDim.x + threadIdx.x;
    size_t base = i4 * 4;
    int c = (int)((base / S_) % C_);
    float4 xv = *(const float4*)(x + base);
    bf16x4 pv = *(const bf16x4*)(p + base);
    float s = sc[c], h = sh[c];
    float4 ov;
    ov.x = xv.x + (float)pv[0] * s + h;
    ov.y = xv.y + (float)pv[1] * s + h;
    ov.z = xv.z + (float)pv[2] * s + h;
    ov.w = xv.w + (float)pv[3] * s + h;
    *(float4*)(out + base) = ov;
}

extern "C" void kernel_launch(void* const* d_in, const int* in_sizes, int n_in,
                              void* d_out, int out_size, void* d_ws, size_t ws_size,
                              hipStream_t stream)
{
    const float* x       = (const float*)d_in[0];
    const float* w_theta = (const float*)d_in[1];
    const float* b_theta = (const float*)d_in[2];
    const float* w_phi   = (const float*)d_in[3];
    const float* b_phi   = (const float*)d_in[4];
    const float* w_g     = (const float*)d_in[5];
    const float* b_g     = (const float*)d_in[6];
    const float* w_out   = (const float*)d_in[7];
    const float* b_out   = (const float*)d_in[8];
    const float* gamma   = (const float*)d_in[9];
    const float* beta    = (const float*)d_in[10];

    char* ws = (char*)d_ws;
    const size_t sz1 = (size_t)N_ * S_ * CI_ * 2;   // 12,845,056 B
    __bf16* theta = (__bf16*)(ws);
    __bf16* phi   = (__bf16*)(ws + sz1);
    __bf16* gT    = (__bf16*)(ws + 2 * sz1);
    __bf16* Opart = (__bf16*)(ws + 3 * sz1);        // 2 splits, 2*sz1
    __bf16* p     = (__bf16*)(ws);                  // overlays theta+phi (dead after attn)
    float* lpart  = (float*)(ws + 5 * sz1);         // 2*N*S floats = 200,704 B
    float* ssum   = (float*)(ws + 5 * sz1 + 2 * (size_t)N_ * S_ * sizeof(float));
    float* ssq = ssum + 512;
    float* scv = ssum + 1024;
    float* shv = ssum + 1536;

    zero_stats<<<1, 1024, 0, stream>>>(ssum);
    qkv_kernel<<<dim3(98, 2, 4), 256, 0, stream>>>(
        x, w_theta, b_theta, w_phi, b_phi, w_g, b_g, theta, phi, gT);
    attn_kernel<<<dim3(784, 1, 1), 256, 38400, stream>>>(theta, phi, gT, Opart, lpart);
    pgemm_kernel<<<dim3(98, 4, 4), 256, 0, stream>>>(Opart, lpart, w_out, b_out, p, ssum, ssq);
    stats_kernel<<<1, 512, 0, stream>>>(ssum, ssq, gamma, beta, scv, shv);
    apply_kernel<<<12544, 256, 0, stream>>>(x, p, scv, shv, (float*)d_out);
}

// Round 3
// 691.959 us; speedup vs baseline: 1.6112x; 1.6112x over previous
//
#include <hip/hip_runtime.h>
#include <hip/hip_bf16.h>

#define N_ 4
#define C_ 512
#define CI_ 256
#define S_ 6272
#define EPS_ 1e-5f
#define NKT 98        // key tiles (of 32) per split; 2 splits * 98 * 32 = 6272

typedef __attribute__((ext_vector_type(8))) __bf16 bf16x8;
typedef __attribute__((ext_vector_type(4))) __bf16 bf16x4;
typedef __attribute__((ext_vector_type(4))) float f32x4;

#define MFMA(a, b, c) __builtin_amdgcn_mfma_f32_16x16x32_bf16(a, b, c, 0, 0, 0)

__device__ __forceinline__ void gl_lds16(const void* g, void* l) {
    __builtin_amdgcn_global_load_lds(
        (const __attribute__((address_space(1))) void*)g,
        (__attribute__((address_space(3))) void*)l, 16, 0, 0);
}

// barrier that drains only LDS ops (leaves global_load_lds DMAs in flight)
#define BARRIER_LGKM() asm volatile("s_waitcnt lgkmcnt(0)\n\ts_barrier" ::: "memory")
// order-only fence: my LDS reads are in registers before anything after this issues
#define FENCE_LGKM()   asm volatile("s_waitcnt lgkmcnt(0)" ::: "memory")
// full-drain barrier: all my DMAs landed; barrier -> everyone's landed
#define BARRIER_VM0()  asm volatile("s_waitcnt vmcnt(0)\n\ts_barrier" ::: "memory")

// ---------------- Kernel 1: QKV projections ----------------
// M = ci (128/block), N = s (64/block), K = c.  Outputs:
//   theta[n][s][ci], phi[n][s][ci] (bf16, PRE-SCALED by 0.25 each; exact since
//   0.25 is a power of two -> theta.phi = scores * ci^-0.5 directly)
//   gT[n][ci][s] (bf16)
__global__ __launch_bounds__(256) void qkv_kernel(
    const float* __restrict__ x,
    const float* __restrict__ w_theta, const float* __restrict__ b_theta,
    const float* __restrict__ w_phi,   const float* __restrict__ b_phi,
    const float* __restrict__ w_g,     const float* __restrict__ b_g,
    __bf16* __restrict__ theta, __bf16* __restrict__ phi, __bf16* __restrict__ gT)
{
    const int s0  = blockIdx.x * 64;
    const int ci0 = blockIdx.y * 128;
    const int n   = blockIdx.z;
    const int tid = threadIdx.x;
    const int wave = tid >> 6, lane = tid & 63;
    const int m16 = lane & 15, quad = lane >> 4;

    __shared__ __bf16 xT[64][40];  // [s-local][c-local(32)], pad->40

    const float* wptr[3] = {w_theta, w_phi, w_g};

    f32x4 acc[3][2][4];
    #pragma unroll
    for (int j = 0; j < 3; ++j)
        #pragma unroll
        for (int ct = 0; ct < 2; ++ct)
            #pragma unroll
            for (int ss = 0; ss < 4; ++ss) acc[j][ct][ss] = f32x4{0.f, 0.f, 0.f, 0.f};

    const int ci_row[2] = {ci0 + wave * 16 + m16, ci0 + 64 + wave * 16 + m16};

    for (int kc = 0; kc < 16; ++kc) {
        __syncthreads();
        // stage x[n][kc*32+c][s0..s0+64] -> xT[s][c]  (float4 along s)
        #pragma unroll
        for (int it = 0; it < 2; ++it) {
            int c_loc = it * 16 + (tid >> 4);
            int s4 = (tid & 15) * 4;
            float4 v = *(const float4*)&x[((size_t)n * C_ + kc * 32 + c_loc) * S_ + s0 + s4];
            xT[s4 + 0][c_loc] = (__bf16)v.x;
            xT[s4 + 1][c_loc] = (__bf16)v.y;
            xT[s4 + 2][c_loc] = (__bf16)v.z;
            xT[s4 + 3][c_loc] = (__bf16)v.w;
        }
        __syncthreads();

        bf16x8 afr[3][2];
        #pragma unroll
        for (int j = 0; j < 3; ++j)
            #pragma unroll
            for (int ct = 0; ct < 2; ++ct) {
                const float* wp = wptr[j] + (size_t)ci_row[ct] * C_ + kc * 32 + quad * 8;
                float4 wa = *(const float4*)wp;
                float4 wb = *(const float4*)(wp + 4);
                bf16x8 t;
                t[0] = (__bf16)wa.x; t[1] = (__bf16)wa.y; t[2] = (__bf16)wa.z; t[3] = (__bf16)wa.w;
                t[4] = (__bf16)wb.x; t[5] = (__bf16)wb.y; t[6] = (__bf16)wb.z; t[7] = (__bf16)wb.w;
                afr[j][ct] = t;
            }
        #pragma unroll
        for (int ss = 0; ss < 4; ++ss) {
            bf16x8 bfr = *(const bf16x8*)&xT[ss * 16 + m16][quad * 8];
            #pragma unroll
            for (int j = 0; j < 3; ++j)
                #pragma unroll
                for (int ct = 0; ct < 2; ++ct)
                    acc[j][ct][ss] = MFMA(afr[j][ct], bfr, acc[j][ct][ss]);
        }
    }

    #pragma unroll
    for (int ct = 0; ct < 2; ++ct) {
        const int ci_base = ci0 + ct * 64 + wave * 16 + quad * 4;
        float bth[4], bph[4], bgg[4];
        #pragma unroll
        for (int r = 0; r < 4; ++r) {
            bth[r] = b_theta[ci_base + r];
            bph[r] = b_phi[ci_base + r];
            bgg[r] = b_g[ci_base + r];
        }
        #pragma unroll
        for (int ss = 0; ss < 4; ++ss) {
            int s = s0 + ss * 16 + m16;
            bf16x4 tv, pv;
            #pragma unroll
            for (int r = 0; r < 4; ++r) {
                tv[r] = (__bf16)((acc[0][ct][ss][r] + bth[r]) * 0.25f);
                pv[r] = (__bf16)((acc[1][ct][ss][r] + bph[r]) * 0.25f);
            }
            *(bf16x4*)&theta[((size_t)n * S_ + s) * CI_ + ci_base] = tv;
            *(bf16x4*)&phi[((size_t)n * S_ + s) * CI_ + ci_base]   = pv;
            #pragma unroll
            for (int r = 0; r < 4; ++r)
                gT[((size_t)n * CI_ + ci_base + r) * S_ + s] = (__bf16)(acc[2][ct][ss][r] + bgg[r]);
        }
    }
}

// ---------------- Kernel 2: flash attention ----------------
// R7: occupancy fix done RIGHT.  R2's launch_bounds(256,4) capped the UNIFIED
// VGPR+AGPR file at 128/wave; true need ~168 (qreg 64 + o-accum 64 + ~40) ->
// in-loop scratch spill (VGPR 64, FETCH 2.1 GB, 817 us).  gfx950's register
// file is unified -- AGPR accumulators count.  Correct target: 3 waves/SIMD
// (budget 512/3 = 170 >= need).  LDS 38.4 KB allows 4 blocks; registers allow
// 3 -> 3 blocks/CU = 12 waves/CU (1.5x R1's 8).
// To give the allocator slack (170 vs 168 is thin), PV's V-fragments are
// loaded in two 2-subtile phases (R0's proven g-loop: FENCE, then re-stage
// those 2 chunks) -> live vf halves, unified need ~152.
// Hazard scheme (R0-proven, 32-key, single-buffered K and V):
//   * top BARRIER_VM0: my 8 DMAs (K(t),V(t), issued last iter) landed; barrier
//     -> everyone's landed (DMAs ride ~half an iteration, covers L2 latency).
//   * mid BARRIER_LGKM: P visible; all waves' kf reads drained -> K overwrite
//     safe.  STAGE_K(t+1) immediately after, rides through PV.
//   * V rows are WAVE-PRIVATE (wave stages and reads only rows [w*64,+64));
//     per g-phase: FENCE_LGKM puts own vf reads in registers -> re-stage of
//     exactly those 2 row-chunks is safe.
//   * P WAR: pf consumed (compiler waitcnt before PV MFMA) before this wave
//     reaches the next top barrier; writes happen only after that barrier.
// XCD swizzle kept: grp = bid&7 = (n,split) -> one XCD each (R1: FETCH 4x
// drop confirms); K/V panel 3.2 MB < 4 MB XCD-L2.
__global__ __launch_bounds__(256, 3) void attn_kernel(
    const __bf16* __restrict__ theta, const __bf16* __restrict__ phi,
    const __bf16* __restrict__ gT, __bf16* __restrict__ Opart, float* __restrict__ lpart)
{
    const int bid = blockIdx.x;
    const int grp = bid & 7;            // (n,split) group -> XCD grp
    const int q0 = (bid >> 3) * 64;
    const int n = grp >> 1;
    const int split = grp & 1;
    const int tid = threadIdx.x;
    const int w = tid >> 6, lane = tid & 63;
    const int m16 = lane & 15, quad = lane >> 4;
    const int xr = m16 & 7;
    const int h = w & 1, kh = w >> 1;

    extern __shared__ char smem[];
    __bf16* k_lds = (__bf16*)smem;                  // [32][256] swizzled (16384 B)
    __bf16* v_lds = (__bf16*)(smem + 16384);        // [256][32] swizzled (16384 B)
    __bf16* p_lds = (__bf16*)(smem + 32768);        // [64][40]  (5120 B)
    float*  lsum  = (float*)(smem + 37888);         // [64][2]   (512 B)

    // ---- Q B-frags: this wave's 32 queries (q-half h) -> 64 VGPR ----
    bf16x8 qreg[2][8];
    #pragma unroll
    for (int qf = 0; qf < 2; ++qf) {
        const __bf16* qrow = theta + ((size_t)n * S_ + q0 + h * 32 + qf * 16 + m16) * CI_ + quad * 8;
        #pragma unroll
        for (int kk = 0; kk < 8; ++kk) qreg[qf][kk] = *(const bf16x8*)(qrow + kk * 32);
    }

    // ---- staging bases (wave w stages K rows [w*8,+8), V rows [w*64,+64)) ----
    const int krow_loc = lane >> 5;                 // 0..1
    const int kA = (lane & 31) ^ krow_loc;
    const char* kgbase = (const char*)(phi + ((size_t)n * S_ + (size_t)split * 3136 + w * 8) * CI_)
                         + krow_loc * 512;
    char* klbase = (char*)k_lds + w * 4096;

    const int vrow_loc = lane >> 2;                 // 0..15
    const int vchunk = (lane & 3) ^ ((lane >> 3) & 3);   // src chunk = pos ^ ((row>>1)&3)
    const char* vgbase = (const char*)gT + (((size_t)n * CI_ + w * 64 + vrow_loc) * S_
                         + (size_t)split * 3136) * 2 + vchunk * 16;
    char* vlbase = (char*)v_lds + w * 4096;

    #define STAGE_K(kt_) { \
        const char* gk = kgbase + ((size_t)(kt_) << 14); \
        _Pragma("unroll") \
        for (int j = 0; j < 4; ++j) \
            gl_lds16(gk + j * 1024 + ((kA ^ ((2 * j) & 7)) << 4), klbase + j * 1024); \
        }
    #define STAGE_V2(kt_, j0_) { \
        const char* gv = vgbase + (size_t)(kt_) * 64; \
        gl_lds16(gv + (size_t)(j0_) * 200704, vlbase + (j0_) * 1024); \
        gl_lds16(gv + (size_t)((j0_) + 1) * 200704, vlbase + ((j0_) + 1) * 1024); }

    f32x4 o[4][4];  // [c][qf] -> o[ci = w*64+c*16+quad*4+r][q = qf*16+m16]
    #pragma unroll
    for (int c = 0; c < 4; ++c)
        #pragma unroll
        for (int qf = 0; qf < 4; ++qf) o[c][qf] = f32x4{0.f, 0.f, 0.f, 0.f};
    float l_part[2] = {0.f, 0.f};

    const __bf16* krow_base = k_lds + ((kh * 16 + m16) << 8);
    const __bf16* vrow_base = v_lds + ((w * 64 + m16) << 5) + ((quad ^ ((m16 >> 1) & 3)) << 3);

    // prologue: tile 0 in flight (8 DMAs)
    STAGE_K(0); STAGE_V2(0, 0); STAGE_V2(0, 2);

    for (int kt = 0; kt < NKT; ++kt) {
        BARRIER_VM0();   // K(t), V(t) staged & visible in all waves; p_lds WAR

        // ---- QK^T quadrant: D[m = key kh*16+quad*4+r][n = q-half h, qf*16+m16] ----
        f32x4 sc[2];
        sc[0] = f32x4{0.f, 0.f, 0.f, 0.f};
        sc[1] = f32x4{0.f, 0.f, 0.f, 0.f};
        #pragma unroll
        for (int kk = 0; kk < 8; ++kk) {
            bf16x8 kf = *(const bf16x8*)(krow_base + (((kk * 4 + quad) ^ xr) << 3));
            sc[0] = MFMA(kf, qreg[0][kk], sc[0]);
            sc[1] = MFMA(kf, qreg[1][kk], sc[1]);
        }

        // ---- exp (pre-scaled scores, no max shift), l accum, P -> LDS [q][key] ----
        #pragma unroll
        for (int qf = 0; qf < 2; ++qf) {
            bf16x4 pk;
            float ls = 0.f;
            #pragma unroll
            for (int r = 0; r < 4; ++r) {
                float e = __expf(sc[qf][r]);
                ls += e;
                pk[r] = (__bf16)e;
            }
            l_part[qf] += ls;
            *(bf16x4*)&p_lds[(h * 32 + qf * 16 + m16) * 40 + kh * 16 + quad * 4] = pk;
        }
        BARRIER_LGKM();   // P visible; all waves' kf reads drained -> K buffer free

        if (kt + 1 < NKT) STAGE_K(kt + 1);   // rides through PV, drains at next top barrier

        // ---- PV: D[m = ci(own 64)][n = q 64] over k = 32; V in 2 fenced phases ----
        bf16x8 pf[4];
        #pragma unroll
        for (int qf = 0; qf < 4; ++qf)
            pf[qf] = *(const bf16x8*)&p_lds[(qf * 16 + m16) * 40 + quad * 8];
        #pragma unroll
        for (int g = 0; g < 2; ++g) {
            bf16x8 vf[2];
            #pragma unroll
            for (int cc = 0; cc < 2; ++cc)
                vf[cc] = *(const bf16x8*)(vrow_base + (g * 2 + cc) * 512);
            if (kt + 1 < NKT) {
                FENCE_LGKM();                 // vf (and pf) in registers -> rows free
                STAGE_V2(kt + 1, 2 * g);
            }
            #pragma unroll
            for (int cc = 0; cc < 2; ++cc)
                #pragma unroll
                for (int qf = 0; qf < 4; ++qf)
                    o[g * 2 + cc][qf] = MFMA(vf[cc], pf[qf], o[g * 2 + cc][qf]);
        }
    }

    // ---- l: sum over quads (own 16 keys), then combine key-halves via LDS ----
    #pragma unroll
    for (int qf = 0; qf < 2; ++qf) {
        float l = l_part[qf];
        l += __shfl_xor(l, 16);
        l += __shfl_xor(l, 32);
        if (quad == 0) lsum[(h * 32 + qf * 16 + m16) * 2 + kh] = l;
    }
    __syncthreads();
    if (tid < 64)
        lpart[((size_t)split * N_ + n) * S_ + q0 + tid] = lsum[tid * 2] + lsum[tid * 2 + 1];

    // ---- store unnormalized O partial ----
    __bf16* Op = Opart + (size_t)split * N_ * S_ * CI_;
    #pragma unroll
    for (int c = 0; c < 4; ++c)
        #pragma unroll
        for (int qf = 0; qf < 4; ++qf) {
            bf16x4 ov;
            #pragma unroll
            for (int r = 0; r < 4; ++r) ov[r] = (__bf16)o[c][qf][r];
            *(bf16x4*)&Op[((size_t)n * S_ + q0 + qf * 16 + m16) * CI_ + w * 64 + c * 16 + quad * 4] = ov;
        }
}

// ---------------- Kernel 3: w_out GEMM + fused split-combine + BN partial stats ----------------
__global__ __launch_bounds__(256) void pgemm_kernel(
    const __bf16* __restrict__ Opart, const float* __restrict__ lpart,
    const float* __restrict__ w_out, const float* __restrict__ b_out,
    __bf16* __restrict__ p, float* __restrict__ ssum, float* __restrict__ ssq)
{
    const int s0 = blockIdx.x * 64;
    const int c0 = blockIdx.y * 128;
    const int n  = blockIdx.z;
    const int tid = threadIdx.x;
    const int wave = tid >> 6, lane = tid & 63;
    const int m16 = lane & 15, quad = lane >> 4;

    __shared__ __bf16 o_lds[64][264];

    const __bf16* O0 = Opart;
    const __bf16* O1 = Opart + (size_t)N_ * S_ * CI_;
    #pragma unroll
    for (int it = 0; it < 8; ++it) {
        int idx = it * 256 + tid;
        int row = idx >> 5, ch = idx & 31;
        size_t ns = (size_t)n * S_ + s0 + row;
        float li = 1.0f / (lpart[ns] + lpart[(size_t)N_ * S_ + ns]);
        bf16x8 a = *(const bf16x8*)&O0[ns * CI_ + ch * 8];
        bf16x8 b = *(const bf16x8*)&O1[ns * CI_ + ch * 8];
        bf16x8 t;
        #pragma unroll
        for (int e = 0; e < 8; ++e) t[e] = (__bf16)(((float)a[e] + (float)b[e]) * li);
        *(bf16x8*)&o_lds[row][ch * 8] = t;
    }
    __syncthreads();

    #pragma unroll
    for (int ct = 0; ct < 2; ++ct) {
        const int c_row = c0 + ct * 64 + wave * 16 + m16;
        bf16x8 af[8];
        #pragma unroll
        for (int kk = 0; kk < 8; ++kk) {
            const float* wp = w_out + (size_t)c_row * CI_ + kk * 32 + quad * 8;
            float4 wa = *(const float4*)wp;
            float4 wb = *(const float4*)(wp + 4);
            bf16x8 t;
            t[0] = (__bf16)wa.x; t[1] = (__bf16)wa.y; t[2] = (__bf16)wa.z; t[3] = (__bf16)wa.w;
            t[4] = (__bf16)wb.x; t[5] = (__bf16)wb.y; t[6] = (__bf16)wb.z; t[7] = (__bf16)wb.w;
            af[kk] = t;
        }
        f32x4 acc[4];
        #pragma unroll
        for (int ss = 0; ss < 4; ++ss) acc[ss] = f32x4{0.f, 0.f, 0.f, 0.f};
        #pragma unroll
        for (int ss = 0; ss < 4; ++ss)
            #pragma unroll
            for (int kk = 0; kk < 8; ++kk) {
                bf16x8 bfr = *(const bf16x8*)&o_lds[ss * 16 + m16][kk * 32 + quad * 8];
                acc[ss] = MFMA(af[kk], bfr, acc[ss]);
            }

        const int c_base = c0 + ct * 64 + wave * 16 + quad * 4;
        float bo[4];
        #pragma unroll
        for (int r = 0; r < 4; ++r) bo[r] = b_out[c_base + r];
        float psum[4] = {0.f, 0.f, 0.f, 0.f}, psq[4] = {0.f, 0.f, 0.f, 0.f};
        #pragma unroll
        for (int ss = 0; ss < 4; ++ss) {
            int s = s0 + ss * 16 + m16;
            #pragma unroll
            for (int r = 0; r < 4; ++r) {
                float v = acc[ss][r] + bo[r];
                __bf16 vb = (__bf16)v;
                p[((size_t)n * C_ + c_base + r) * S_ + s] = vb;
                float vr = (float)vb;
                psum[r] += vr;
                psq[r]  += vr * vr;
            }
        }
        #pragma unroll
        for (int r = 0; r < 4; ++r) {
            #pragma unroll
            for (int off = 1; off < 16; off <<= 1) {
                psum[r] += __shfl_xor(psum[r], off);
                psq[r]  += __shfl_xor(psq[r], off);
            }
        }
        if (m16 == 0) {
            #pragma unroll
            for (int r = 0; r < 4; ++r) {
                atomicAdd(&ssum[c_base + r], psum[r]);
                atomicAdd(&ssq[c_base + r],  psq[r]);
            }
        }
    }
}

// ---------------- small kernels ----------------
__global__ void zero_stats(float* ptr) {
    ptr[blockIdx.x * blockDim.x + threadIdx.x] = 0.0f;
}

__global__ void stats_kernel(const float* __restrict__ ssum, const float* __restrict__ ssq,
                             const float* __restrict__ gamma, const float* __restrict__ beta,
                             float* __restrict__ sc, float* __restrict__ sh)
{
    int c = threadIdx.x;  // 512
    const float inv_m = 1.0f / (float)((size_t)N_ * S_);
    float mean = ssum[c] * inv_m;
    float var = ssq[c] * inv_m - mean * mean;
    var = fmaxf(var, 0.0f);
    float inv = rsqrtf(var + EPS_);
    float g = gamma[c];
    sc[c] = inv * g;
    sh[c] = beta[c] - mean * inv * g;
}

__global__ __launch_bounds__(256) void apply_kernel(
    const float* __restrict__ x, const __bf16* __restrict__ p,
    const float* __restrict__ sc, const float* __restrict__ sh,
    float* __restrict__ out)
{
    size_t i4 = (size_t)blockIdx.x * blockDim.x + threadIdx.x;
    size_t base = i4 * 4;
    int c = (int)((base / S_) % C_);
    float4 xv = *(const float4*)(x + base);
    bf16x4 pv = *(const bf16x4*)(p + base);
    float s = sc[c], h = sh[c];
    float4 ov;
    ov.x = xv.x + (float)pv[0] * s + h;
    ov.y = xv.y + (float)pv[1] * s + h;
    ov.z = xv.z + (float)pv[2] * s + h;
    ov.w = xv.w + (float)pv[3] * s + h;
    *(float4*)(out + base) = ov;
}

extern "C" void kernel_launch(void* const* d_in, const int* in_sizes, int n_in,
                              void* d_out, int out_size, void* d_ws, size_t ws_size,
                              hipStream_t stream)
{
    const float* x       = (const float*)d_in[0];
    const float* w_theta = (const float*)d_in[1];
    const float* b_theta = (const float*)d_in[2];
    const float* w_phi   = (const float*)d_in[3];
    const float* b_phi   = (const float*)d_in[4];
    const float* w_g     = (const float*)d_in[5];
    const float* b_g     = (const float*)d_in[6];
    const float* w_out   = (const float*)d_in[7];
    const float* b_out   = (const float*)d_in[8];
    const float* gamma   = (const float*)d_in[9];
    const float* beta    = (const float*)d_in[10];

    char* ws = (char*)d_ws;
    const size_t sz1 = (size_t)N_ * S_ * CI_ * 2;   // 12,845,056 B
    __bf16* theta = (__bf16*)(ws);
    __bf16* phi   = (__bf16*)(ws + sz1);
    __bf16* gT    = (__bf16*)(ws + 2 * sz1);
    __bf16* Opart = (__bf16*)(ws + 3 * sz1);        // 2 splits, 2*sz1
    __bf16* p     = (__bf16*)(ws);                  // overlays theta+phi (dead after attn)
    float* lpart  = (float*)(ws + 5 * sz1);         // 2*N*S floats = 200,704 B
    float* ssum   = (float*)(ws + 5 * sz1 + 2 * (size_t)N_ * S_ * sizeof(float));
    float* ssq = ssum + 512;
    float* scv = ssum + 1024;
    float* shv = ssum + 1536;

    zero_stats<<<1, 1024, 0, stream>>>(ssum);
    qkv_kernel<<<dim3(98, 2, 4), 256, 0, stream>>>(
        x, w_theta, b_theta, w_phi, b_phi, w_g, b_g, theta, phi, gT);
    attn_kernel<<<dim3(784, 1, 1), 256, 38400, stream>>>(theta, phi, gT, Opart, lpart);
    pgemm_kernel<<<dim3(98, 4, 4), 256, 0, stream>>>(Opart, lpart, w_out, b_out, p, ssum, ssq);
    stats_kernel<<<1, 512, 0, stream>>>(ssum, ssq, gamma, beta, scv, shv);
    apply_kernel<<<12544, 256, 0, stream>>>(x, p, scv, shv, (float*)d_out);
}

// Round 4
// 589.958 us; speedup vs baseline: 1.8898x; 1.1729x over previous
//
#include <hip/hip_runtime.h>
#include <hip/hip_bf16.h>

#define N_ 4
#define C_ 512
#define CI_ 256
#define S_ 6272
#define EPS_ 1e-5f
#define NKT 98        // key tiles (of 32) per split; 2 splits * 98 * 32 = 6272

typedef __attribute__((ext_vector_type(8))) __bf16 bf16x8;
typedef __attribute__((ext_vector_type(4))) __bf16 bf16x4;
typedef __attribute__((ext_vector_type(4))) float f32x4;
typedef __attribute__((ext_vector_type(4))) unsigned int u32x4;

#define MFMA(a, b, c) __builtin_amdgcn_mfma_f32_16x16x32_bf16(a, b, c, 0, 0, 0)

__device__ __forceinline__ void gl_lds16(const void* g, void* l) {
    __builtin_amdgcn_global_load_lds(
        (const __attribute__((address_space(1))) void*)g,
        (__attribute__((address_space(3))) void*)l, 16, 0, 0);
}

// full-drain barrier: all my DMAs landed; barrier -> everyone's landed
#define BARRIER_VM0()  asm volatile("s_waitcnt vmcnt(0)\n\ts_barrier" ::: "memory")

__device__ __forceinline__ unsigned pack2(float x, float y) {
    __bf16 a = (__bf16)x, b = (__bf16)y;
    return (unsigned)__builtin_bit_cast(unsigned short, a)
         | ((unsigned)__builtin_bit_cast(unsigned short, b) << 16);
}

// ---------------- Kernel 1: QKV projections ----------------
// M = ci (128/block), N = s (64/block), K = c.  Outputs:
//   theta[n][s][ci], phi[n][s][ci] (bf16, PRE-SCALED by 0.25 each; exact since
//   0.25 is a power of two -> theta.phi = scores * ci^-0.5 directly)
//   gT[n][ci][s] (bf16)
__global__ __launch_bounds__(256) void qkv_kernel(
    const float* __restrict__ x,
    const float* __restrict__ w_theta, const float* __restrict__ b_theta,
    const float* __restrict__ w_phi,   const float* __restrict__ b_phi,
    const float* __restrict__ w_g,     const float* __restrict__ b_g,
    __bf16* __restrict__ theta, __bf16* __restrict__ phi, __bf16* __restrict__ gT)
{
    const int s0  = blockIdx.x * 64;
    const int ci0 = blockIdx.y * 128;
    const int n   = blockIdx.z;
    const int tid = threadIdx.x;
    const int wave = tid >> 6, lane = tid & 63;
    const int m16 = lane & 15, quad = lane >> 4;

    __shared__ __bf16 xT[64][40];  // [s-local][c-local(32)], pad->40

    const float* wptr[3] = {w_theta, w_phi, w_g};

    f32x4 acc[3][2][4];
    #pragma unroll
    for (int j = 0; j < 3; ++j)
        #pragma unroll
        for (int ct = 0; ct < 2; ++ct)
            #pragma unroll
            for (int ss = 0; ss < 4; ++ss) acc[j][ct][ss] = f32x4{0.f, 0.f, 0.f, 0.f};

    const int ci_row[2] = {ci0 + wave * 16 + m16, ci0 + 64 + wave * 16 + m16};

    for (int kc = 0; kc < 16; ++kc) {
        __syncthreads();
        // stage x[n][kc*32+c][s0..s0+64] -> xT[s][c]  (float4 along s)
        #pragma unroll
        for (int it = 0; it < 2; ++it) {
            int c_loc = it * 16 + (tid >> 4);
            int s4 = (tid & 15) * 4;
            float4 v = *(const float4*)&x[((size_t)n * C_ + kc * 32 + c_loc) * S_ + s0 + s4];
            xT[s4 + 0][c_loc] = (__bf16)v.x;
            xT[s4 + 1][c_loc] = (__bf16)v.y;
            xT[s4 + 2][c_loc] = (__bf16)v.z;
            xT[s4 + 3][c_loc] = (__bf16)v.w;
        }
        __syncthreads();

        bf16x8 afr[3][2];
        #pragma unroll
        for (int j = 0; j < 3; ++j)
            #pragma unroll
            for (int ct = 0; ct < 2; ++ct) {
                const float* wp = wptr[j] + (size_t)ci_row[ct] * C_ + kc * 32 + quad * 8;
                float4 wa = *(const float4*)wp;
                float4 wb = *(const float4*)(wp + 4);
                bf16x8 t;
                t[0] = (__bf16)wa.x; t[1] = (__bf16)wa.y; t[2] = (__bf16)wa.z; t[3] = (__bf16)wa.w;
                t[4] = (__bf16)wb.x; t[5] = (__bf16)wb.y; t[6] = (__bf16)wb.z; t[7] = (__bf16)wb.w;
                afr[j][ct] = t;
            }
        #pragma unroll
        for (int ss = 0; ss < 4; ++ss) {
            bf16x8 bfr = *(const bf16x8*)&xT[ss * 16 + m16][quad * 8];
            #pragma unroll
            for (int j = 0; j < 3; ++j)
                #pragma unroll
                for (int ct = 0; ct < 2; ++ct)
                    acc[j][ct][ss] = MFMA(afr[j][ct], bfr, acc[j][ct][ss]);
        }
    }

    #pragma unroll
    for (int ct = 0; ct < 2; ++ct) {
        const int ci_base = ci0 + ct * 64 + wave * 16 + quad * 4;
        float bth[4], bph[4], bgg[4];
        #pragma unroll
        for (int r = 0; r < 4; ++r) {
            bth[r] = b_theta[ci_base + r];
            bph[r] = b_phi[ci_base + r];
            bgg[r] = b_g[ci_base + r];
        }
        #pragma unroll
        for (int ss = 0; ss < 4; ++ss) {
            int s = s0 + ss * 16 + m16;
            bf16x4 tv, pv;
            #pragma unroll
            for (int r = 0; r < 4; ++r) {
                tv[r] = (__bf16)((acc[0][ct][ss][r] + bth[r]) * 0.25f);
                pv[r] = (__bf16)((acc[1][ct][ss][r] + bph[r]) * 0.25f);
            }
            *(bf16x4*)&theta[((size_t)n * S_ + s) * CI_ + ci_base] = tv;
            *(bf16x4*)&phi[((size_t)n * S_ + s) * CI_ + ci_base]   = pv;
            #pragma unroll
            for (int r = 0; r < 4; ++r)
                gT[((size_t)n * CI_ + ci_base + r) * S_ + s] = (__bf16)(acc[2][ct][ss][r] + bgg[r]);
        }
    }
}

// ---------------- Kernel 2: flash attention ----------------
// R8 restructure (wave-self-contained, P-in-register):
//   Each wave owns 16 QUERIES x all 32 keys of the tile (not a 32q x 16k
//   quadrant).  QK: D[m=key][n=own q16]: sc0 = keys quad*4+r, sc1 = +16.
//   PV's B-operand (keys on the K-axis, own q on n) is assembled IN-REGISTER:
//   key 8*quad+j lives at source lane (2*(quad&1)+(j>=4))*16+m16, slot
//   (sub=quad>>1, r=j&3) -> 8 __shfl (u32 bf16-pairs) + 4 selects.  This
//   DELETES p_lds, DELETES the mid barrier, and decouples waves completely:
//   ONE barrier per 32-key tile.
//   Pipeline: dbuf K and V (LDS 2x16K + 2x16K = 64 KB, 2 blocks/CU).
//   Loop: [vmcnt(0)+barrier: tile t landed, everyone past reads of t-1]
//         -> STAGE(t+1) into buf[t-1's slot] (safe; rides a FULL iteration)
//         -> QK(reads K[t]) -> exp/shuffle (no LDS) -> PV(reads V[t]).
//   No launch_bounds min-wave cap (R2/R3 lesson: unified VGPR+AGPR file;
//   caps cause in-loop scratch spill).  Need ~130 regs (qreg halves to 32).
//   T5 setprio around MFMA clusters: waves of the 2 resident blocks desync
//   across the whole tile body -> scheduler has roles to arbitrate (m191).
//   XCD swizzle kept (R1: FETCH 4x drop): grp = bid&7 -> one XCD per
//   (n,split); K/V panel 3.2 MB < 4 MB XCD-L2.
__global__ __launch_bounds__(256) void attn_kernel(
    const __bf16* __restrict__ theta, const __bf16* __restrict__ phi,
    const __bf16* __restrict__ gT, __bf16* __restrict__ Opart, float* __restrict__ lpart)
{
    const int bid = blockIdx.x;
    const int grp = bid & 7;            // (n,split) group -> XCD grp
    const int q0 = (bid >> 3) * 64;
    const int n = grp >> 1;
    const int split = grp & 1;
    const int tid = threadIdx.x;
    const int w = tid >> 6, lane = tid & 63;
    const int m16 = lane & 15, quad = lane >> 4;
    const int xr = m16 & 7;

    extern __shared__ char smem[];
    char* k_lds = smem;                 // 2 x [32][256] bf16, swizzled (2x16384 B)
    char* v_lds = smem + 32768;         // 2 x [256][32] bf16, swizzled (2x16384 B)

    // ---- Q B-frags: this wave's 16 queries -> 32 VGPR ----
    bf16x8 qreg[8];
    {
        const __bf16* qrow = theta + ((size_t)n * S_ + q0 + w * 16 + m16) * CI_ + quad * 8;
        #pragma unroll
        for (int kk = 0; kk < 8; ++kk) qreg[kk] = *(const bf16x8*)(qrow + kk * 32);
    }

    // ---- staging bases (wave w stages K rows [w*8,+8), V rows [w*64,+64)) ----
    const int krow_loc = lane >> 5;                 // 0..1
    const int kA = (lane & 31) ^ krow_loc;
    const char* kgbase = (const char*)(phi + ((size_t)n * S_ + (size_t)split * 3136 + w * 8) * CI_)
                         + krow_loc * 512;
    char* klbase = k_lds + w * 4096;

    const int vrow_loc = lane >> 2;                 // 0..15
    const int vchunk = (lane & 3) ^ ((lane >> 3) & 3);   // src chunk = pos ^ ((row>>1)&3)
    const char* vgbase = (const char*)gT + (((size_t)n * CI_ + w * 64 + vrow_loc) * S_
                         + (size_t)split * 3136) * 2 + vchunk * 16;
    char* vlbase = v_lds + w * 4096;

    #define STAGE_K(bf_, kt_) { \
        const char* gk = kgbase + ((size_t)(kt_) << 14); \
        char* kl = klbase + (bf_) * 16384; \
        _Pragma("unroll") \
        for (int j = 0; j < 4; ++j) \
            gl_lds16(gk + j * 1024 + ((kA ^ ((2 * j) & 7)) << 4), kl + j * 1024); \
        }
    #define STAGE_V(bf_, kt_) { \
        const char* gv = vgbase + (size_t)(kt_) * 64; \
        char* vl = vlbase + (bf_) * 16384; \
        _Pragma("unroll") \
        for (int j = 0; j < 4; ++j) \
            gl_lds16(gv + (size_t)j * 200704, vl + j * 1024); \
        }

    f32x4 o[16];  // o[ct] -> O[ci = ct*16+quad*4+r][q = w*16+m16]
    #pragma unroll
    for (int ct = 0; ct < 16; ++ct) o[ct] = f32x4{0.f, 0.f, 0.f, 0.f};
    float l_acc = 0.f;

    const int krow0 = m16 * 512;                    // K row m16 (sub0); +8192 for sub1
    const int vsw = (quad ^ ((m16 >> 1) & 3)) << 4; // V chunk swizzle (byte)
    const int l0 = ((quad & 1) << 5) | m16;         // shuffle src lanes
    const int l1 = l0 + 16;
    const bool hi = quad >= 2;

    // prologue: tile 0 in flight (8 DMAs/wave)
    STAGE_K(0, 0); STAGE_V(0, 0);

    for (int kt = 0; kt < NKT; ++kt) {
        const int buf = kt & 1;
        BARRIER_VM0();   // K(t),V(t) landed everywhere; everyone past reads of t-1

        if (kt + 1 < NKT) {            // stage into buf[t-1's slot]; rides full iter
            STAGE_K(buf ^ 1, kt + 1);
            STAGE_V(buf ^ 1, kt + 1);
        }

        // ---- QK^T: D[m=key][n=own q].  sc0: keys quad*4+r, sc1: 16+quad*4+r ----
        const char* kbb = k_lds + buf * 16384;
        f32x4 sc0 = f32x4{0.f, 0.f, 0.f, 0.f};
        f32x4 sc1 = f32x4{0.f, 0.f, 0.f, 0.f};
        __builtin_amdgcn_s_setprio(1);
        #pragma unroll
        for (int kk = 0; kk < 8; ++kk) {
            const int ch = ((kk * 4 + quad) ^ xr) << 4;
            bf16x8 kf0 = *(const bf16x8*)(kbb + krow0 + ch);
            bf16x8 kf1 = *(const bf16x8*)(kbb + 8192 + krow0 + ch);
            sc0 = MFMA(kf0, qreg[kk], sc0);
            sc1 = MFMA(kf1, qreg[kk], sc1);
        }
        __builtin_amdgcn_s_setprio(0);

        // ---- exp (pre-scaled scores, no max shift); P stays in registers ----
        float e0[4], e1[4];
        float ls = 0.f;
        #pragma unroll
        for (int r = 0; r < 4; ++r) {
            e0[r] = __expf(sc0[r]);
            e1[r] = __expf(sc1[r]);
            ls += e0[r] + e1[r];
        }
        l_acc += ls;

        // ---- assemble PV B-frag via quad-swap shuffles (8 shfl + 4 sel) ----
        unsigned a01 = pack2(e0[0], e0[1]), a23 = pack2(e0[2], e0[3]);
        unsigned b01 = pack2(e1[0], e1[1]), b23 = pack2(e1[2], e1[3]);
        unsigned r0a = (unsigned)__shfl((int)a01, l0), r0b = (unsigned)__shfl((int)b01, l0);
        unsigned r1a = (unsigned)__shfl((int)a23, l0), r1b = (unsigned)__shfl((int)b23, l0);
        unsigned r2a = (unsigned)__shfl((int)a01, l1), r2b = (unsigned)__shfl((int)b01, l1);
        unsigned r3a = (unsigned)__shfl((int)a23, l1), r3b = (unsigned)__shfl((int)b23, l1);
        u32x4 pbw;
        pbw[0] = hi ? r0b : r0a;
        pbw[1] = hi ? r1b : r1a;
        pbw[2] = hi ? r2b : r2a;
        pbw[3] = hi ? r3b : r3a;
        bf16x8 pb = __builtin_bit_cast(bf16x8, pbw);

        // ---- PV: D[m=ci 256][n=own q16]; A = V^T tiles from LDS ----
        const char* vbb = v_lds + buf * 16384 + vsw;
        __builtin_amdgcn_s_setprio(1);
        #pragma unroll
        for (int ct = 0; ct < 16; ++ct) {
            bf16x8 vf = *(const bf16x8*)(vbb + (ct * 16 + m16) * 64);
            o[ct] = MFMA(vf, pb, o[ct]);
        }
        __builtin_amdgcn_s_setprio(0);
    }

    // ---- l: in-lane sum done; combine quads; wave owns its 16 q -> direct store ----
    {
        float l = l_acc;
        l += __shfl_xor(l, 16);
        l += __shfl_xor(l, 32);
        if (quad == 0)
            lpart[((size_t)split * N_ + n) * S_ + q0 + w * 16 + m16] = l;
    }

    // ---- store unnormalized O partial ----
    __bf16* Op = Opart + (size_t)split * N_ * S_ * CI_;
    const size_t orow = ((size_t)n * S_ + q0 + w * 16 + m16) * CI_;
    #pragma unroll
    for (int ct = 0; ct < 16; ++ct) {
        bf16x4 ov;
        #pragma unroll
        for (int r = 0; r < 4; ++r) ov[r] = (__bf16)o[ct][r];
        *(bf16x4*)&Op[orow + ct * 16 + quad * 4] = ov;
    }
}

// ---------------- Kernel 3: w_out GEMM + fused split-combine + BN partial stats ----------------
__global__ __launch_bounds__(256) void pgemm_kernel(
    const __bf16* __restrict__ Opart, const float* __restrict__ lpart,
    const float* __restrict__ w_out, const float* __restrict__ b_out,
    __bf16* __restrict__ p, float* __restrict__ ssum, float* __restrict__ ssq)
{
    const int s0 = blockIdx.x * 64;
    const int c0 = blockIdx.y * 128;
    const int n  = blockIdx.z;
    const int tid = threadIdx.x;
    const int wave = tid >> 6, lane = tid & 63;
    const int m16 = lane & 15, quad = lane >> 4;

    __shared__ __bf16 o_lds[64][264];

    const __bf16* O0 = Opart;
    const __bf16* O1 = Opart + (size_t)N_ * S_ * CI_;
    #pragma unroll
    for (int it = 0; it < 8; ++it) {
        int idx = it * 256 + tid;
        int row = idx >> 5, ch = idx & 31;
        size_t ns = (size_t)n * S_ + s0 + row;
        float li = 1.0f / (lpart[ns] + lpart[(size_t)N_ * S_ + ns]);
        bf16x8 a = *(const bf16x8*)&O0[ns * CI_ + ch * 8];
        bf16x8 b = *(const bf16x8*)&O1[ns * CI_ + ch * 8];
        bf16x8 t;
        #pragma unroll
        for (int e = 0; e < 8; ++e) t[e] = (__bf16)(((float)a[e] + (float)b[e]) * li);
        *(bf16x8*)&o_lds[row][ch * 8] = t;
    }
    __syncthreads();

    #pragma unroll
    for (int ct = 0; ct < 2; ++ct) {
        const int c_row = c0 + ct * 64 + wave * 16 + m16;
        bf16x8 af[8];
        #pragma unroll
        for (int kk = 0; kk < 8; ++kk) {
            const float* wp = w_out + (size_t)c_row * CI_ + kk * 32 + quad * 8;
            float4 wa = *(const float4*)wp;
            float4 wb = *(const float4*)(wp + 4);
            bf16x8 t;
            t[0] = (__bf16)wa.x; t[1] = (__bf16)wa.y; t[2] = (__bf16)wa.z; t[3] = (__bf16)wa.w;
            t[4] = (__bf16)wb.x; t[5] = (__bf16)wb.y; t[6] = (__bf16)wb.z; t[7] = (__bf16)wb.w;
            af[kk] = t;
        }
        f32x4 acc[4];
        #pragma unroll
        for (int ss = 0; ss < 4; ++ss) acc[ss] = f32x4{0.f, 0.f, 0.f, 0.f};
        #pragma unroll
        for (int ss = 0; ss < 4; ++ss)
            #pragma unroll
            for (int kk = 0; kk < 8; ++kk) {
                bf16x8 bfr = *(const bf16x8*)&o_lds[ss * 16 + m16][kk * 32 + quad * 8];
                acc[ss] = MFMA(af[kk], bfr, acc[ss]);
            }

        const int c_base = c0 + ct * 64 + wave * 16 + quad * 4;
        float bo[4];
        #pragma unroll
        for (int r = 0; r < 4; ++r) bo[r] = b_out[c_base + r];
        float psum[4] = {0.f, 0.f, 0.f, 0.f}, psq[4] = {0.f, 0.f, 0.f, 0.f};
        #pragma unroll
        for (int ss = 0; ss < 4; ++ss) {
            int s = s0 + ss * 16 + m16;
            #pragma unroll
            for (int r = 0; r < 4; ++r) {
                float v = acc[ss][r] + bo[r];
                __bf16 vb = (__bf16)v;
                p[((size_t)n * C_ + c_base + r) * S_ + s] = vb;
                float vr = (float)vb;
                psum[r] += vr;
                psq[r]  += vr * vr;
            }
        }
        #pragma unroll
        for (int r = 0; r < 4; ++r) {
            #pragma unroll
            for (int off = 1; off < 16; off <<= 1) {
                psum[r] += __shfl_xor(psum[r], off);
                psq[r]  += __shfl_xor(psq[r], off);
            }
        }
        if (m16 == 0) {
            #pragma unroll
            for (int r = 0; r < 4; ++r) {
                atomicAdd(&ssum[c_base + r], psum[r]);
                atomicAdd(&ssq[c_base + r],  psq[r]);
            }
        }
    }
}

// ---------------- small kernels ----------------
__global__ void zero_stats(float* ptr) {
    ptr[blockIdx.x * blockDim.x + threadIdx.x] = 0.0f;
}

__global__ void stats_kernel(const float* __restrict__ ssum, const float* __restrict__ ssq,
                             const float* __restrict__ gamma, const float* __restrict__ beta,
                             float* __restrict__ sc, float* __restrict__ sh)
{
    int c = threadIdx.x;  // 512
    const float inv_m = 1.0f / (float)((size_t)N_ * S_);
    float mean = ssum[c] * inv_m;
    float var = ssq[c] * inv_m - mean * mean;
    var = fmaxf(var, 0.0f);
    float inv = rsqrtf(var + EPS_);
    float g = gamma[c];
    sc[c] = inv * g;
    sh[c] = beta[c] - mean * inv * g;
}

__global__ __launch_bounds__(256) void apply_kernel(
    const float* __restrict__ x, const __bf16* __restrict__ p,
    const float* __restrict__ sc, const float* __restrict__ sh,
    float* __restrict__ out)
{
    size_t i4 = (size_t)blockIdx.x * blockDim.x + threadIdx.x;
    size_t base = i4 * 4;
    int c = (int)((base / S_) % C_);
    float4 xv = *(const float4*)(x + base);
    bf16x4 pv = *(const bf16x4*)(p + base);
    float s = sc[c], h = sh[c];
    float4 ov;
    ov.x = xv.x + (float)pv[0] * s + h;
    ov.y = xv.y + (float)pv[1] * s + h;
    ov.z = xv.z + (float)pv[2] * s + h;
    ov.w = xv.w + (float)pv[3] * s + h;
    *(float4*)(out + base) = ov;
}

extern "C" void kernel_launch(void* const* d_in, const int* in_sizes, int n_in,
                              void* d_out, int out_size, void* d_ws, size_t ws_size,
                              hipStream_t stream)
{
    const float* x       = (const float*)d_in[0];
    const float* w_theta = (const float*)d_in[1];
    const float* b_theta = (const float*)d_in[2];
    const float* w_phi   = (const float*)d_in[3];
    const float* b_phi   = (const float*)d_in[4];
    const float* w_g     = (const float*)d_in[5];
    const float* b_g     = (const float*)d_in[6];
    const float* w_out   = (const float*)d_in[7];
    const float* b_out   = (const float*)d_in[8];
    const float* gamma   = (const float*)d_in[9];
    const float* beta    = (const float*)d_in[10];

    char* ws = (char*)d_ws;
    const size_t sz1 = (size_t)N_ * S_ * CI_ * 2;   // 12,845,056 B
    __bf16* theta = (__bf16*)(ws);
    __bf16* phi   = (__bf16*)(ws + sz1);
    __bf16* gT    = (__bf16*)(ws + 2 * sz1);
    __bf16* Opart = (__bf16*)(ws + 3 * sz1);        // 2 splits, 2*sz1
    __bf16* p     = (__bf16*)(ws);                  // overlays theta+phi (dead after attn)
    float* lpart  = (float*)(ws + 5 * sz1);         // 2*N*S floats = 200,704 B
    float* ssum   = (float*)(ws + 5 * sz1 + 2 * (size_t)N_ * S_ * sizeof(float));
    float* ssq = ssum + 512;
    float* scv = ssum + 1024;
    float* shv = ssum + 1536;

    zero_stats<<<1, 1024, 0, stream>>>(ssum);
    qkv_kernel<<<dim3(98, 2, 4), 256, 0, stream>>>(
        x, w_theta, b_theta, w_phi, b_phi, w_g, b_g, theta, phi, gT);
    hipFuncSetAttribute((const void*)attn_kernel,
                        hipFuncAttributeMaxDynamicSharedMemorySize, 65536);
    attn_kernel<<<dim3(784, 1, 1), 256, 65536, stream>>>(theta, phi, gT, Opart, lpart);
    pgemm_kernel<<<dim3(98, 4, 4), 256, 0, stream>>>(Opart, lpart, w_out, b_out, p, ssum, ssq);
    stats_kernel<<<1, 512, 0, stream>>>(ssum, ssq, gamma, beta, scv, shv);
    apply_kernel<<<12544, 256, 0, stream>>>(x, p, scv, shv, (float*)d_out);
}

// Round 5
// 507.511 us; speedup vs baseline: 2.1968x; 1.1625x over previous
//
#include <hip/hip_runtime.h>
#include <hip/hip_bf16.h>

#define N_ 4
#define C_ 512
#define CI_ 256
#define S_ 6272
#define EPS_ 1e-5f
#define NKT 49        // key tiles (of 64) per split; 2 splits * 49 * 64 = 6272

typedef __attribute__((ext_vector_type(8))) __bf16 bf16x8;
typedef __attribute__((ext_vector_type(4))) __bf16 bf16x4;
typedef __attribute__((ext_vector_type(4))) float f32x4;

#define MFMA(a, b, c) __builtin_amdgcn_mfma_f32_16x16x32_bf16(a, b, c, 0, 0, 0)

__device__ __forceinline__ void gl_lds16(const void* g, void* l) {
    __builtin_amdgcn_global_load_lds(
        (const __attribute__((address_space(1))) void*)g,
        (__attribute__((address_space(3))) void*)l, 16, 0, 0);
}

// barrier that drains only LDS ops (leaves global_load_lds DMAs in flight)
#define BARRIER_LGKM() asm volatile("s_waitcnt lgkmcnt(0)\n\ts_barrier" ::: "memory")
// order-only fence: my LDS reads are in registers before anything after this issues
#define FENCE_LGKM()   asm volatile("s_waitcnt lgkmcnt(0)" ::: "memory")

// ---------------- Kernel 1: QKV projections ----------------
// M = ci (128/block), N = s (64/block), K = c.  Outputs:
//   theta[n][s][ci], phi[n][s][ci] (bf16, PRE-SCALED by 0.25 each; exact since
//   0.25 is a power of two -> theta.phi = scores * ci^-0.5 directly)
//   gT[n][ci][s] (bf16)
// R9: x-staging software-pipelined -- the float4 loads for kc+1 are issued
// right after the compute barrier and land in registers; their ~700cy HBM/L3
// latency hides under the kc MFMA+weight phase instead of serializing
// between the two barriers (was: sync -> load -> use immediately).
__global__ __launch_bounds__(256) void qkv_kernel(
    const float* __restrict__ x,
    const float* __restrict__ w_theta, const float* __restrict__ b_theta,
    const float* __restrict__ w_phi,   const float* __restrict__ b_phi,
    const float* __restrict__ w_g,     const float* __restrict__ b_g,
    __bf16* __restrict__ theta, __bf16* __restrict__ phi, __bf16* __restrict__ gT)
{
    const int s0  = blockIdx.x * 64;
    const int ci0 = blockIdx.y * 128;
    const int n   = blockIdx.z;
    const int tid = threadIdx.x;
    const int wave = tid >> 6, lane = tid & 63;
    const int m16 = lane & 15, quad = lane >> 4;

    __shared__ __bf16 xT[64][40];  // [s-local][c-local(32)], pad->40

    const float* wptr[3] = {w_theta, w_phi, w_g};

    f32x4 acc[3][2][4];
    #pragma unroll
    for (int j = 0; j < 3; ++j)
        #pragma unroll
        for (int ct = 0; ct < 2; ++ct)
            #pragma unroll
            for (int ss = 0; ss < 4; ++ss) acc[j][ct][ss] = f32x4{0.f, 0.f, 0.f, 0.f};

    const int ci_row[2] = {ci0 + wave * 16 + m16, ci0 + 64 + wave * 16 + m16};

    // staging geometry (constant across kc)
    const int c_loc0 = tid >> 4;          // 0..15 (it adds +16)
    const int s4 = (tid & 15) * 4;
    const float* xbase = x + ((size_t)n * C_ + c_loc0) * S_ + s0 + s4;

    float4 pre[2];
    #pragma unroll
    for (int it = 0; it < 2; ++it)
        pre[it] = *(const float4*)(xbase + (size_t)(it * 16) * S_);

    for (int kc = 0; kc < 16; ++kc) {
        __syncthreads();     // readers of previous tile done
        #pragma unroll
        for (int it = 0; it < 2; ++it) {
            int c_loc = it * 16 + c_loc0;
            xT[s4 + 0][c_loc] = (__bf16)pre[it].x;
            xT[s4 + 1][c_loc] = (__bf16)pre[it].y;
            xT[s4 + 2][c_loc] = (__bf16)pre[it].z;
            xT[s4 + 3][c_loc] = (__bf16)pre[it].w;
        }
        __syncthreads();     // tile visible

        if (kc + 1 < 16) {   // prefetch kc+1; latency rides under compute below
            #pragma unroll
            for (int it = 0; it < 2; ++it)
                pre[it] = *(const float4*)(xbase + (size_t)((kc + 1) * 32 + it * 16) * S_);
        }

        bf16x8 afr[3][2];
        #pragma unroll
        for (int j = 0; j < 3; ++j)
            #pragma unroll
            for (int ct = 0; ct < 2; ++ct) {
                const float* wp = wptr[j] + (size_t)ci_row[ct] * C_ + kc * 32 + quad * 8;
                float4 wa = *(const float4*)wp;
                float4 wb = *(const float4*)(wp + 4);
                bf16x8 t;
                t[0] = (__bf16)wa.x; t[1] = (__bf16)wa.y; t[2] = (__bf16)wa.z; t[3] = (__bf16)wa.w;
                t[4] = (__bf16)wb.x; t[5] = (__bf16)wb.y; t[6] = (__bf16)wb.z; t[7] = (__bf16)wb.w;
                afr[j][ct] = t;
            }
        #pragma unroll
        for (int ss = 0; ss < 4; ++ss) {
            bf16x8 bfr = *(const bf16x8*)&xT[ss * 16 + m16][quad * 8];
            #pragma unroll
            for (int j = 0; j < 3; ++j)
                #pragma unroll
                for (int ct = 0; ct < 2; ++ct)
                    acc[j][ct][ss] = MFMA(afr[j][ct], bfr, acc[j][ct][ss]);
        }
    }

    #pragma unroll
    for (int ct = 0; ct < 2; ++ct) {
        const int ci_base = ci0 + ct * 64 + wave * 16 + quad * 4;
        float bth[4], bph[4], bgg[4];
        #pragma unroll
        for (int r = 0; r < 4; ++r) {
            bth[r] = b_theta[ci_base + r];
            bph[r] = b_phi[ci_base + r];
            bgg[r] = b_g[ci_base + r];
        }
        #pragma unroll
        for (int ss = 0; ss < 4; ++ss) {
            int s = s0 + ss * 16 + m16;
            bf16x4 tv, pv;
            #pragma unroll
            for (int r = 0; r < 4; ++r) {
                tv[r] = (__bf16)((acc[0][ct][ss][r] + bth[r]) * 0.25f);
                pv[r] = (__bf16)((acc[1][ct][ss][r] + bph[r]) * 0.25f);
            }
            *(bf16x4*)&theta[((size_t)n * S_ + s) * CI_ + ci_base] = tv;
            *(bf16x4*)&phi[((size_t)n * S_ + s) * CI_ + ci_base]   = pv;
            #pragma unroll
            for (int r = 0; r < 4; ++r)
                gT[((size_t)n * CI_ + ci_base + r) * S_ + s] = (__bf16)(acc[2][ct][ss][r] + bgg[r]);
        }
    }
}

// ---------------- Kernel 2: flash attention ----------------
// R9 = R0's proven kernel (228us, best of 5 rounds) + T5 setprio around the
// MFMA clusters (m191: attn +4-7%, zero correctness risk).  Four structural
// rewrites (R5-R8: XCD swizzle, counted-vmcnt dbuf, 4blk occupancy, P-in-reg)
// all lost to this decomposition; see round notes.
// Block: 64 queries, 4 waves; split handles 49 key tiles of 64.
// QK: wave = (q-half h=w&1, key-half kh=w>>1): 32x32 score quadrant.
//     Each kf b128 feeds 2 MFMAs (1:2 read:MFMA).  qreg = 64 VGPR (no remat).
// PV: wave w owns ci [64w,+64), all 64 q; V rows self-staged/self-read.
// RACE scheme: every V-prefetch DMA preceded by FENCE_LGKM so the wave's own
// vf ds_reads are in registers before the DMA overwrites the rows.
// K-prefetch after mid-barrier (all waves' kf reads provably drained there).
// No max-subtraction softmax; outputs unnormalized O + l partials.
__global__ __launch_bounds__(256, 2) void attn_kernel(
    const __bf16* __restrict__ theta, const __bf16* __restrict__ phi,
    const __bf16* __restrict__ gT, __bf16* __restrict__ Opart, float* __restrict__ lpart)
{
    const int q0 = blockIdx.x * 64;
    const int split = blockIdx.y;
    const int n  = blockIdx.z;
    const int tid = threadIdx.x;
    const int w = tid >> 6, lane = tid & 63;
    const int m16 = lane & 15, quad = lane >> 4;
    const int xr = m16 & 7;
    const int h = w & 1, kh = w >> 1;

    extern __shared__ char smem[];
    __bf16* k_lds = (__bf16*)smem;                  // [64][256] swizzled
    __bf16* v_lds = (__bf16*)(smem + 32768);        // [256][64] swizzled
    __bf16* p_lds = (__bf16*)(smem + 65536);        // [64][72]  (9216 B)
    float*  lsum  = (float*)(smem + 74752);         // [64][2]   (512 B)

    // ---- Q B-frags: this wave's 32 queries (q-half h) -> 64 VGPR ----
    bf16x8 qreg[2][8];
    #pragma unroll
    for (int qf = 0; qf < 2; ++qf) {
        const __bf16* qrow = theta + ((size_t)n * S_ + q0 + h * 32 + qf * 16 + m16) * CI_ + quad * 8;
        #pragma unroll
        for (int kk = 0; kk < 8; ++kk) qreg[qf][kk] = *(const bf16x8*)(qrow + kk * 32);
    }

    // ---- staging bases (wave w stages K rows [w*16,+16), V rows [w*64,+64)) ----
    const int krow_loc = lane >> 5;                 // 0..1
    const int kA = (lane & 31) ^ krow_loc;
    const char* kgbase = (const char*)(phi + ((size_t)n * S_ + (size_t)split * 3136 + w * 16) * CI_)
                         + krow_loc * 512;
    char* klbase = (char*)k_lds + w * 8192;
    const int vrow_loc = lane >> 3;                 // 0..7
    const int vjsrc = (lane & 7) ^ vrow_loc;
    const char* vgbase = (const char*)gT + (((size_t)n * CI_ + w * 64 + vrow_loc) * S_
                         + (size_t)split * 3136) * 2 + vjsrc * 16;
    char* vlbase = (char*)v_lds + w * 8192;

    #define STAGE_K(kt_) { \
        const char* gk = kgbase + ((size_t)(kt_) << 15); \
        _Pragma("unroll") \
        for (int j = 0; j < 8; ++j) { \
            int jsrc = kA ^ ((2 * j) & 7); \
            gl_lds16(gk + j * 1024 + jsrc * 16, klbase + j * 1024); \
        } }
    #define STAGE_V2(kt_, j0_) { \
        const char* gv = vgbase + (size_t)(kt_) * 128; \
        gl_lds16(gv + (size_t)(j0_) * 100352, vlbase + (j0_) * 1024); \
        gl_lds16(gv + (size_t)((j0_) + 1) * 100352, vlbase + ((j0_) + 1) * 1024); }

    f32x4 o[4][4];  // [c][qf] -> o[ci = w*64+c*16+quad*4+r][q = qf*16+m16]
    #pragma unroll
    for (int c = 0; c < 4; ++c)
        #pragma unroll
        for (int qf = 0; qf < 4; ++qf) o[c][qf] = f32x4{0.f, 0.f, 0.f, 0.f};
    float l_part[2] = {0.f, 0.f};

    const __bf16* vrow_ptr = v_lds + (w * 64 + m16) * 64;    // + c*1024 per c-subtile

    STAGE_K(0);
    STAGE_V2(0, 0); STAGE_V2(0, 2); STAGE_V2(0, 4); STAGE_V2(0, 6);

    for (int kt = 0; kt < NKT; ++kt) {
        __syncthreads();   // drains own vmcnt -> all K/V staged & visible; p_lds WAR

        // ---- QK^T quadrant: D[m = key kh*32+sub*16+..][n = q-half h, qf*16+m16] ----
        f32x4 sc[2][2];
        #pragma unroll
        for (int sub = 0; sub < 2; ++sub)
            #pragma unroll
            for (int qf = 0; qf < 2; ++qf) sc[sub][qf] = f32x4{0.f, 0.f, 0.f, 0.f};
        __builtin_amdgcn_s_setprio(1);
        #pragma unroll
        for (int kk = 0; kk < 8; ++kk) {
            #pragma unroll
            for (int sub = 0; sub < 2; ++sub) {
                bf16x8 kf = *(const bf16x8*)&k_lds[(kh * 32 + sub * 16 + m16) * 256
                                                   + (((kk * 4 + quad) ^ xr) << 3)];
                #pragma unroll
                for (int qf = 0; qf < 2; ++qf)
                    sc[sub][qf] = MFMA(kf, qreg[qf][kk], sc[sub][qf]);
            }
        }
        __builtin_amdgcn_s_setprio(0);

        // ---- exp (pre-scaled scores, no max shift), l accum, P -> LDS [q][key] ----
        #pragma unroll
        for (int sub = 0; sub < 2; ++sub)
            #pragma unroll
            for (int qf = 0; qf < 2; ++qf) {
                bf16x4 pk;
                float ls = 0.f;
                #pragma unroll
                for (int r = 0; r < 4; ++r) {
                    float e = __expf(sc[sub][qf][r]);
                    ls += e;
                    pk[r] = (__bf16)e;
                }
                l_part[qf] += ls;
                *(bf16x4*)&p_lds[(h * 32 + qf * 16 + m16) * 72 + kh * 32 + sub * 16 + quad * 4] = pk;
            }
        BARRIER_LGKM();   // all P visible; all waves' kf reads drained -> K overwrite safe

        if (kt + 1 < NKT) STAGE_K(kt + 1);   // rides through PV, drains at next top barrier

        // ---- PV: D[m = ci(own 64)][n = q 64]; V prefetch fenced per half ----
        bf16x8 pf[4][2];
        #pragma unroll
        for (int qf = 0; qf < 4; ++qf)
            #pragma unroll
            for (int kk2 = 0; kk2 < 2; ++kk2)
                pf[qf][kk2] = *(const bf16x8*)&p_lds[(qf * 16 + m16) * 72 + kk2 * 32 + quad * 8];
        #pragma unroll
        for (int g = 0; g < 2; ++g) {
            bf16x8 vf[2][2];
            #pragma unroll
            for (int cc = 0; cc < 2; ++cc)
                #pragma unroll
                for (int kk2 = 0; kk2 < 2; ++kk2)
                    vf[cc][kk2] = *(const bf16x8*)(vrow_ptr + (g * 2 + cc) * 1024
                                                   + (((kk2 * 4 + quad) ^ xr) << 3));
            if (kt + 1 < NKT) {
                FENCE_LGKM();                 // vf (and pf) in registers -> safe to overwrite
                STAGE_V2(kt + 1, 4 * g);
                STAGE_V2(kt + 1, 4 * g + 2);
            }
            __builtin_amdgcn_s_setprio(1);
            #pragma unroll
            for (int cc = 0; cc < 2; ++cc)
                #pragma unroll
                for (int kk2 = 0; kk2 < 2; ++kk2)
                    #pragma unroll
                    for (int qf = 0; qf < 4; ++qf)
                        o[g * 2 + cc][qf] = MFMA(vf[cc][kk2], pf[qf][kk2], o[g * 2 + cc][qf]);
            __builtin_amdgcn_s_setprio(0);
        }
    }

    // ---- l: sum over quads (own 32 keys), then combine key-halves via LDS ----
    #pragma unroll
    for (int qf = 0; qf < 2; ++qf) {
        float l = l_part[qf];
        l += __shfl_xor(l, 16);
        l += __shfl_xor(l, 32);
        if (quad == 0) lsum[(h * 32 + qf * 16 + m16) * 2 + kh] = l;
    }
    __syncthreads();
    if (tid < 64)
        lpart[((size_t)split * N_ + n) * S_ + q0 + tid] = lsum[tid * 2] + lsum[tid * 2 + 1];

    // ---- store unnormalized O partial ----
    __bf16* Op = Opart + (size_t)split * N_ * S_ * CI_;
    #pragma unroll
    for (int c = 0; c < 4; ++c)
        #pragma unroll
        for (int qf = 0; qf < 4; ++qf) {
            bf16x4 ov;
            #pragma unroll
            for (int r = 0; r < 4; ++r) ov[r] = (__bf16)o[c][qf][r];
            *(bf16x4*)&Op[((size_t)n * S_ + q0 + qf * 16 + m16) * CI_ + w * 64 + c * 16 + quad * 4] = ov;
        }
}

// ---------------- Kernel 3: w_out GEMM + fused split-combine + BN partial stats ----------------
__global__ __launch_bounds__(256) void pgemm_kernel(
    const __bf16* __restrict__ Opart, const float* __restrict__ lpart,
    const float* __restrict__ w_out, const float* __restrict__ b_out,
    __bf16* __restrict__ p, float* __restrict__ ssum, float* __restrict__ ssq)
{
    const int s0 = blockIdx.x * 64;
    const int c0 = blockIdx.y * 128;
    const int n  = blockIdx.z;
    const int tid = threadIdx.x;
    const int wave = tid >> 6, lane = tid & 63;
    const int m16 = lane & 15, quad = lane >> 4;

    __shared__ __bf16 o_lds[64][264];

    const __bf16* O0 = Opart;
    const __bf16* O1 = Opart + (size_t)N_ * S_ * CI_;
    #pragma unroll
    for (int it = 0; it < 8; ++it) {
        int idx = it * 256 + tid;
        int row = idx >> 5, ch = idx & 31;
        size_t ns = (size_t)n * S_ + s0 + row;
        float li = 1.0f / (lpart[ns] + lpart[(size_t)N_ * S_ + ns]);
        bf16x8 a = *(const bf16x8*)&O0[ns * CI_ + ch * 8];
        bf16x8 b = *(const bf16x8*)&O1[ns * CI_ + ch * 8];
        bf16x8 t;
        #pragma unroll
        for (int e = 0; e < 8; ++e) t[e] = (__bf16)(((float)a[e] + (float)b[e]) * li);
        *(bf16x8*)&o_lds[row][ch * 8] = t;
    }
    __syncthreads();

    #pragma unroll
    for (int ct = 0; ct < 2; ++ct) {
        const int c_row = c0 + ct * 64 + wave * 16 + m16;
        bf16x8 af[8];
        #pragma unroll
        for (int kk = 0; kk < 8; ++kk) {
            const float* wp = w_out + (size_t)c_row * CI_ + kk * 32 + quad * 8;
            float4 wa = *(const float4*)wp;
            float4 wb = *(const float4*)(wp + 4);
            bf16x8 t;
            t[0] = (__bf16)wa.x; t[1] = (__bf16)wa.y; t[2] = (__bf16)wa.z; t[3] = (__bf16)wa.w;
            t[4] = (__bf16)wb.x; t[5] = (__bf16)wb.y; t[6] = (__bf16)wb.z; t[7] = (__bf16)wb.w;
            af[kk] = t;
        }
        f32x4 acc[4];
        #pragma unroll
        for (int ss = 0; ss < 4; ++ss) acc[ss] = f32x4{0.f, 0.f, 0.f, 0.f};
        #pragma unroll
        for (int ss = 0; ss < 4; ++ss)
            #pragma unroll
            for (int kk = 0; kk < 8; ++kk) {
                bf16x8 bfr = *(const bf16x8*)&o_lds[ss * 16 + m16][kk * 32 + quad * 8];
                acc[ss] = MFMA(af[kk], bfr, acc[ss]);
            }

        const int c_base = c0 + ct * 64 + wave * 16 + quad * 4;
        float bo[4];
        #pragma unroll
        for (int r = 0; r < 4; ++r) bo[r] = b_out[c_base + r];
        float psum[4] = {0.f, 0.f, 0.f, 0.f}, psq[4] = {0.f, 0.f, 0.f, 0.f};
        #pragma unroll
        for (int ss = 0; ss < 4; ++ss) {
            int s = s0 + ss * 16 + m16;
            #pragma unroll
            for (int r = 0; r < 4; ++r) {
                float v = acc[ss][r] + bo[r];
                __bf16 vb = (__bf16)v;
                p[((size_t)n * C_ + c_base + r) * S_ + s] = vb;
                float vr = (float)vb;
                psum[r] += vr;
                psq[r]  += vr * vr;
            }
        }
        #pragma unroll
        for (int r = 0; r < 4; ++r) {
            #pragma unroll
            for (int off = 1; off < 16; off <<= 1) {
                psum[r] += __shfl_xor(psum[r], off);
                psq[r]  += __shfl_xor(psq[r], off);
            }
        }
        if (m16 == 0) {
            #pragma unroll
            for (int r = 0; r < 4; ++r) {
                atomicAdd(&ssum[c_base + r], psum[r]);
                atomicAdd(&ssq[c_base + r],  psq[r]);
            }
        }
    }
}

// ---------------- small kernels ----------------
__global__ void zero_stats(float* ptr) {
    ptr[blockIdx.x * blockDim.x + threadIdx.x] = 0.0f;
}

__global__ void stats_kernel(const float* __restrict__ ssum, const float* __restrict__ ssq,
                             const float* __restrict__ gamma, const float* __restrict__ beta,
                             float* __restrict__ sc, float* __restrict__ sh)
{
    int c = threadIdx.x;  // 512
    const float inv_m = 1.0f / (float)((size_t)N_ * S_);
    float mean = ssum[c] * inv_m;
    float var = ssq[c] * inv_m - mean * mean;
    var = fmaxf(var, 0.0f);
    float inv = rsqrtf(var + EPS_);
    float g = gamma[c];
    sc[c] = inv * g;
    sh[c] = beta[c] - mean * inv * g;
}

// R9: 3D grid (s-chunk, c, n) -- no per-thread 64-bit div/mod; sc/sh are
// wave-uniform scalar loads.  Guarded tail (7*1024 = 7168 > 6272).
__global__ __launch_bounds__(256) void apply_kernel(
    const float* __restrict__ x, const __bf16* __restrict__ p,
    const float* __restrict__ sc, const float* __restrict__ sh,
    float* __restrict__ out)
{
    const int c = blockIdx.y, n = blockIdx.z;
    const int s4 = (blockIdx.x * 256 + threadIdx.x) * 4;
    if (s4 >= S_) return;
    const size_t base = ((size_t)n * C_ + c) * S_ + s4;
    const float s = sc[c], h = sh[c];
    float4 xv = *(const float4*)(x + base);
    bf16x4 pv = *(const bf16x4*)(p + base);
    float4 ov;
    ov.x = xv.x + (float)pv[0] * s + h;
    ov.y = xv.y + (float)pv[1] * s + h;
    ov.z = xv.z + (float)pv[2] * s + h;
    ov.w = xv.w + (float)pv[3] * s + h;
    *(float4*)(out + base) = ov;
}

extern "C" void kernel_launch(void* const* d_in, const int* in_sizes, int n_in,
                              void* d_out, int out_size, void* d_ws, size_t ws_size,
                              hipStream_t stream)
{
    const float* x       = (const float*)d_in[0];
    const float* w_theta = (const float*)d_in[1];
    const float* b_theta = (const float*)d_in[2];
    const float* w_phi   = (const float*)d_in[3];
    const float* b_phi   = (const float*)d_in[4];
    const float* w_g     = (const float*)d_in[5];
    const float* b_g     = (const float*)d_in[6];
    const float* w_out   = (const float*)d_in[7];
    const float* b_out   = (const float*)d_in[8];
    const float* gamma   = (const float*)d_in[9];
    const float* beta    = (const float*)d_in[10];

    char* ws = (char*)d_ws;
    const size_t sz1 = (size_t)N_ * S_ * CI_ * 2;   // 12,845,056 B
    __bf16* theta = (__bf16*)(ws);
    __bf16* phi   = (__bf16*)(ws + sz1);
    __bf16* gT    = (__bf16*)(ws + 2 * sz1);
    __bf16* Opart = (__bf16*)(ws + 3 * sz1);        // 2 splits, 2*sz1
    __bf16* p     = (__bf16*)(ws);                  // overlays theta+phi (dead after attn)
    float* lpart  = (float*)(ws + 5 * sz1);         // 2*N*S floats = 200,704 B
    float* ssum   = (float*)(ws + 5 * sz1 + 2 * (size_t)N_ * S_ * sizeof(float));
    float* ssq = ssum + 512;
    float* scv = ssum + 1024;
    float* shv = ssum + 1536;

    zero_stats<<<1, 1024, 0, stream>>>(ssum);
    qkv_kernel<<<dim3(98, 2, 4), 256, 0, stream>>>(
        x, w_theta, b_theta, w_phi, b_phi, w_g, b_g, theta, phi, gT);
    hipFuncSetAttribute((const void*)attn_kernel,
                        hipFuncAttributeMaxDynamicSharedMemorySize, 75776);
    attn_kernel<<<dim3(98, 2, 4), 256, 75776, stream>>>(theta, phi, gT, Opart, lpart);
    pgemm_kernel<<<dim3(98, 4, 4), 256, 0, stream>>>(Opart, lpart, w_out, b_out, p, ssum, ssq);
    stats_kernel<<<1, 512, 0, stream>>>(ssum, ssq, gamma, beta, scv, shv);
    apply_kernel<<<dim3(7, C_, N_), 256, 0, stream>>>(x, p, scv, shv, (float*)d_out);
}